// Round 7
// baseline (2866.506 us; speedup 1.0000x reference)
//
#include <hip/hip_runtime.h>
#include <hip/hip_fp16.h>

typedef _Float16 f16;
typedef _Float16 f16x8 __attribute__((ext_vector_type(8)));
typedef float    f32x4 __attribute__((ext_vector_type(4)));

#define HID 512
#define FEA 128
#define ROWSTR 129            // inputs row = 128 feat + 1 shock
#define SEQL 512
#define DEN1 64
#define NG 8                  // batch groups (16 rows each)
#define MB 16                 // batch rows per group
#define GC 16                 // gate columns per wave
#define SLICES 32             // column slices per group

// workspace (bytes); zeroed every launch
#define WS_FLG    0                         // NG*32 u32 step flags (monotonic)
#define WS_HRING  1024                      // 2*NG*MB*HID f16 = 262144 B
#define WS_END    (WS_HRING + 2*NG*MB*HID*2)

#define MFMA16(a,b,c) __builtin_amdgcn_mfma_f32_16x16x32_f16((a),(b),(c),0,0,0)

__device__ __forceinline__ float sigmoid_f(float x) {
    x = fminf(fmaxf(x, -30.f), 30.f);
    return 1.f / (1.f + __expf(-x));
}
__device__ __forceinline__ float tanh_f(float x) {
    x = fminf(fmaxf(x, -15.f), 15.f);
    float e = __expf(2.f * x);
    return (e - 1.f) / (e + 1.f);
}

// One wave (64 threads) per workgroup. Wave (p, sl) owns gate-columns
// [sl*16, sl*16+16) of groups gA=2p and gB=2p+1, alternating halves.
// All cross-WG sync is wave-private counted-vmcnt (in-order retire, m135):
//   entry state   : [frags(24), flag(1)]          -> vmcnt(1) completes frags
//   + poll(1)     : [flag, poll]
//   + stores(4)   : [flag, poll, st4] = 6         -> vmcnt(4) completes flag+poll
//   + frags(24)   : [st4, frags24] = 28           -> vmcnt(24) completes stores
//   + flag(1)     : [frags24, flag1]  (closes ledger)
__global__ __launch_bounds__(64)
void gru_pipe(const float* __restrict__ inp, const float* __restrict__ Wk,
              const float* __restrict__ Rk,  const float* __restrict__ bias,
              const float* __restrict__ W1,  const float* __restrict__ b1,
              const float* __restrict__ gam, const float* __restrict__ bet,
              const float* __restrict__ mmn, const float* __restrict__ mvr,
              const float* __restrict__ W2,  const float* __restrict__ b2p,
              const float* __restrict__ Wsh, float* __restrict__ out,
              char* __restrict__ ws)
{
    __shared__ __align__(16) f16 Bh[512 * 48];   // 49152 B: R gate-col B-frags

    const int lane = threadIdx.x;
    const int bid  = blockIdx.x;          // 0..127
    const int p    = bid >> 5;            // pair 0..3
    const int sl   = bid & 31;            // slice 0..31
    const int gA   = p * 2, gB = p * 2 + 1;
    const int j0   = sl * GC;
    const int arow = lane & 15, ahalf = lane >> 4;

    unsigned* flg   = (unsigned*)(ws + WS_FLG);
    f16*      hring = (f16*)(ws + WS_HRING);

    // ---- stage Bh (Rk gate-col slice, 48 cols = z|r|h) into LDS frag layout ----
    for (int idx = lane; idx < 512 * 48; idx += 64) {
        int kk = idx / 48, c = idx - kk * 48;
        int col = (c >> 4) * HID + j0 + (c & 15);
        Bh[((kk >> 3) * 48 + c) * 8 + (kk & 7)] = (f16)Rk[(size_t)kk * 1536 + col];
    }
    // ---- Bx (Wk slice, K=128) directly into registers as B-frags ----
    f16x8 bx[3][4];
    #pragma unroll
    for (int gt = 0; gt < 3; ++gt)
        #pragma unroll
        for (int ks = 0; ks < 4; ++ks) {
            f16x8 v;
            #pragma unroll
            for (int e = 0; e < 8; ++e) {
                int k = ks * 32 + ahalf * 8 + e;
                v[e] = (f16)Wk[(size_t)k * 1536 + gt * 512 + j0 + (lane & 15)];
            }
            bx[gt][ks] = v;
        }

    const int cl = j0 + (lane & 15);      // this lane's gate column
    const float bZ  = bias[cl] + bias[1536 + cl];
    const float bRr = bias[512 + cl] + bias[1536 + 512 + cl];
    const float bXH = bias[1024 + cl];
    const float bHH = bias[1536 + 1024 + cl];

    asm volatile("s_waitcnt vmcnt(0) lgkmcnt(0)" ::: "memory");  // staging drained
    __builtin_amdgcn_sched_barrier(0);

    float holdA[4] = {0,0,0,0}, holdB[4] = {0,0,0,0};
    f16x8 af[16];          // h A-frags (single buffer: consumed then refilled)
    f32x4 xf[8];           // x f32 A-data
    unsigned pollv = 0;

    // issue 24 frag loads for (g, t): 16 coherent h + 8 plain x. FIXED ORDER.
    auto issue_frags = [&](int g, int t) {
        const f16* hb = hring + ((size_t)(t & 1) * NG + g) * MB * HID
                              + (size_t)arow * HID + ahalf * 8;
        #pragma unroll
        for (int s = 0; s < 16; ++s)
            asm volatile("global_load_dwordx4 %0, %1, off offset:%c2 sc0 sc1"
                         : "=v"(af[s]) : "v"(hb), "i"(s * 64));
        const float* xb = inp + ((size_t)(g * MB + arow) * SEQL + t) * ROWSTR + ahalf * 8;
        #pragma unroll
        for (int ks = 0; ks < 4; ++ks) {
            asm volatile("global_load_dwordx4 %0, %1, off offset:%c2"
                         : "=v"(xf[ks * 2])     : "v"(xb), "i"(ks * 128));
            asm volatile("global_load_dwordx4 %0, %1, off offset:%c2"
                         : "=v"(xf[ks * 2 + 1]) : "v"(xb), "i"(ks * 128 + 16));
        }
    };
    auto post_flag = [&](int gc, int val) {
        if (lane == 0) {
            unsigned* fp = flg + gc * 32 + sl;
            asm volatile("global_store_dword %0, %1, off sc0 sc1"
                         :: "v"(fp), "v"((unsigned)val) : "memory");
        }
    };

    // one half: compute group gc at step tc; prep group gn at step tn
    auto half = [&](int gc, int tc, int gn, int tn, float (&hold)[4]) {
        asm volatile("s_waitcnt vmcnt(1)" ::: "memory");   // frags(gc,tc) ready
        __builtin_amdgcn_sched_barrier(0);
        if (tn < SEQL) {                                    // early poll issue
            const unsigned* pp = flg + gn * 32 + (lane & 31);
            asm volatile("global_load_dword %0, %1, off sc0 sc1"
                         : "=v"(pollv) : "v"(pp) : "memory");
        }
        // x f32 -> f16 A-frags
        f16x8 xa[4];
        #pragma unroll
        for (int ks = 0; ks < 4; ++ks) {
            f16x8 a;
            #pragma unroll
            for (int e = 0; e < 4; ++e) {
                a[e]     = (f16)xf[ks * 2][e];
                a[4 + e] = (f16)xf[ks * 2 + 1][e];
            }
            xa[ks] = a;
        }
        // 48 h-MFMAs (LDS B) + 12 x-MFMAs (reg B), 4 accumulators
        f32x4 aZ = {0,0,0,0}, aR = {0,0,0,0}, aH = {0,0,0,0}, aX = {0,0,0,0};
        const f16x8* BF = (const f16x8*)Bh;
        #pragma unroll
        for (int ks = 0; ks < 16; ++ks) {
            const f16x8* bp = BF + (ks * 4 + ahalf) * 48 + (lane & 15);
            aZ = MFMA16(af[ks], bp[0],  aZ);
            aR = MFMA16(af[ks], bp[16], aR);
            aH = MFMA16(af[ks], bp[32], aH);
        }
        #pragma unroll
        for (int ks = 0; ks < 4; ++ks) {
            aZ = MFMA16(xa[ks], bx[0][ks], aZ);
            aR = MFMA16(xa[ks], bx[1][ks], aR);
            aX = MFMA16(xa[ks], bx[2][ks], aX);
        }
        // gates + 4 coherent 2B stores; D layout: col=lane&15, row=ahalf*4+i
        f16* hdst = hring + (((size_t)((tc & 1) ^ 1) * NG + gc) * MB) * HID;
        #pragma unroll
        for (int i = 0; i < 4; ++i) {
            float z  = sigmoid_f(aZ[i] + bZ);
            float r  = sigmoid_f(aR[i] + bRr);
            float hc = tanh_f(aX[i] + bXH + r * (aH[i] + bHH));
            float hn = z * hold[i] + (1.f - z) * hc;
            f16 h16 = (f16)hn;
            hold[i] = (float)h16;
            union { f16 h; unsigned short u; } cv; cv.h = h16;
            void* dp = hdst + ((size_t)(ahalf * 4 + i)) * HID + cl;
            asm volatile("global_store_short %0, %1, off sc0 sc1"
                         :: "v"(dp), "v"((unsigned)cv.u) : "memory");
        }
        if (tn < SEQL) {
            asm volatile("s_waitcnt vmcnt(4)" ::: "memory");   // poll (+old flag) done
            __builtin_amdgcn_sched_barrier(0);
            const unsigned want = (unsigned)tn;
            if (!__all((int)(pollv >= want))) {
                // slow path: drain, post our flag early, re-poll until ready
                asm volatile("s_waitcnt vmcnt(0)" ::: "memory");
                __builtin_amdgcn_sched_barrier(0);
                post_flag(gc, tc + 1);
                for (;;) {
                    const unsigned* pp = flg + gn * 32 + (lane & 31);
                    asm volatile("global_load_dword %0, %1, off sc0 sc1"
                                 : "=v"(pollv) : "v"(pp) : "memory");
                    asm volatile("s_waitcnt vmcnt(0)" ::: "memory");
                    __builtin_amdgcn_sched_barrier(0);
                    if (__all((int)(pollv >= want))) break;
                }
                issue_frags(gn, tn);
                post_flag(gc, tc + 1);    // dummy repost keeps ledger shape [frags24, flag1]
            } else {
                issue_frags(gn, tn);
                asm volatile("s_waitcnt vmcnt(24)" ::: "memory");  // h-stores drained
                __builtin_amdgcn_sched_barrier(0);
                post_flag(gc, tc + 1);
            }
        } else {
            asm volatile("s_waitcnt vmcnt(0)" ::: "memory");
            __builtin_amdgcn_sched_barrier(0);
            post_flag(gc, tc + 1);
        }
    };

    // prologue: establish entry state [frags(gA,0) 24, dummy flag 1]
    issue_frags(gA, 0);
    post_flag(gA, 0);   // value 0 == initial, benign

    #pragma unroll 1
    for (int t = 0; t < SEQL; ++t) {
        half(gA, t, gB, t,     holdA);
        half(gB, t, gA, t + 1, holdB);
    }
    asm volatile("s_waitcnt vmcnt(0) lgkmcnt(0)" ::: "memory");
    __builtin_amdgcn_sched_barrier(0);

    // ---- head: waves sl<2 compute group g = 2p+sl fully (deterministic) ----
    if (sl < 2) {
        const int g = 2 * p + sl;
        for (;;) {
            unsigned v;
            asm volatile("global_load_dword %0, %1, off sc0 sc1"
                         : "=v"(v) : "v"(flg + g * 32 + (lane & 31)) : "memory");
            asm volatile("s_waitcnt vmcnt(0)" ::: "memory");
            if (__all((int)(v >= (unsigned)SEQL))) break;
        }
        __builtin_amdgcn_sched_barrier(0);
        // final h is in ring slot 0 (t=511 wrote (511&1)^1 = 0); copy to LDS
        f16* hl = (f16*)Bh;                          // [16][512]
        const f16* hfin = hring + (size_t)g * MB * HID;
        f16x8 hv[16];
        #pragma unroll
        for (int c8 = 0; c8 < 16; ++c8) {
            int chunk = c8 * 64 + lane;              // 1024 chunks of 8 f16
            int row = chunk >> 6, off = (chunk & 63) * 8;
            asm volatile("global_load_dwordx4 %0, %1, off sc0 sc1"
                         : "=v"(hv[c8]) : "v"(hfin + (size_t)row * HID + off));
        }
        asm volatile("s_waitcnt vmcnt(0)" ::: "memory");
        __builtin_amdgcn_sched_barrier(0);
        #pragma unroll
        for (int c8 = 0; c8 < 16; ++c8) {
            int chunk = c8 * 64 + lane;
            int row = chunk >> 6, off = (chunk & 63) * 8;
            *(f16x8*)(hl + (size_t)row * HID + off) = hv[c8];
        }
        float* smq  = (float*)(Bh + 8192);           // 64 floats
        float* redc = smq + 64;                      // 1024 floats
        // shock mean: row r = lane&15, quarter q = lane>>4
        {
            int r = lane & 15, q = lane >> 4;
            float ss = 0.f;
            const float* sp = inp + ((size_t)(g * MB + r) * SEQL + q * 128) * ROWSTR + FEA;
            for (int tt = 0; tt < 128; ++tt) ss += sp[(size_t)tt * ROWSTR];
            smq[q * 16 + r] = ss;
        }
        __syncthreads();
        if (lane < 16)
            smq[lane] = (smq[lane] + smq[16 + lane] + smq[32 + lane] + smq[48 + lane])
                        * (1.f / SEQL);
        __syncthreads();
        // dense1: lane = column c (0..63)
        const int c = lane;
        float acc[16];
        #pragma unroll
        for (int rr = 0; rr < 16; ++rr) acc[rr] = 0.f;
        float wsum = 0.f;
        for (int k8 = 0; k8 < 64; ++k8) {
            f16x8 hrow[16];
            #pragma unroll
            for (int rr = 0; rr < 16; ++rr)
                hrow[rr] = *(const f16x8*)(hl + (size_t)rr * HID + k8 * 8);
            float wv[8];
            #pragma unroll
            for (int e = 0; e < 8; ++e) {
                wv[e] = W1[(size_t)(k8 * 8 + e) * DEN1 + c];
                wsum += wv[e];
            }
            #pragma unroll
            for (int rr = 0; rr < 16; ++rr)
                #pragma unroll
                for (int e = 0; e < 8; ++e)
                    acc[rr] += (float)hrow[rr][e] * wv[e];
        }
        const float WshV = Wsh[0];
        const float w2c = W2[c];
        const float mm = mmn[c], iv = rsqrtf(mvr[c] + 0.001f), gc_ = gam[c], bc = bet[c];
        const float b1c = b1[c];
        #pragma unroll
        for (int rr = 0; rr < 16; ++rr) {
            float d = acc[rr] + smq[rr] * WshV * wsum + b1c;
            d = fmaxf(d, 0.f);
            d = (d - mm) * iv * gc_ + bc;
            redc[c * 16 + rr] = d * w2c;
        }
        __syncthreads();
        if (lane < MB) {
            float o = b2p[0];
            for (int cc = 0; cc < DEN1; ++cc)       // fixed order -> deterministic
                o += redc[cc * 16 + lane];
            out[g * MB + lane] = o;
        }
    }
}

extern "C" void kernel_launch(void* const* d_in, const int* in_sizes, int n_in,
                              void* d_out, int out_size, void* d_ws, size_t ws_size,
                              hipStream_t stream) {
    (void)in_sizes; (void)n_in; (void)out_size; (void)ws_size;
    const float* inp  = (const float*)d_in[0];
    const float* Wk   = (const float*)d_in[1];
    const float* Rk   = (const float*)d_in[2];
    const float* bias = (const float*)d_in[3];
    const float* W1   = (const float*)d_in[4];
    const float* b1   = (const float*)d_in[5];
    const float* gam  = (const float*)d_in[6];
    const float* bet  = (const float*)d_in[7];
    const float* mmn  = (const float*)d_in[8];
    const float* mvr  = (const float*)d_in[9];
    const float* W2   = (const float*)d_in[10];
    const float* b2p  = (const float*)d_in[11];
    const float* Wsh  = (const float*)d_in[12];

    hipMemsetAsync(d_ws, 0, WS_END, stream);   // flags + h0 = 0, every launch
    hipLaunchKernelGGL(gru_pipe, dim3(4 * SLICES), dim3(64), 0, stream,
                       inp, Wk, Rk, bias, W1, b1, gam, bet, mmn, mvr, W2, b2p, Wsh,
                       (float*)d_out, (char*)d_ws);
}